// Round 1
// baseline (320.682 us; speedup 1.0000x reference)
//
#include <hip/hip_runtime.h>
#include <stdint.h>

// STAR-DNN: per-sample scene-selected 3-layer MLP.
// Strategy: compact samples by scene -> per-scene 128-row GEMM tiles,
// bf16 MFMA (16x16x32) with fp32 accum, weights pre-scaled (W*gW) and
// transposed to N x K (K-contiguous) bf16, XOR-swizzled LDS tiles.

#define BATCH   16384
#define NSCENE  7
#define TM      128
#define MT_MAX  (BATCH / TM + NSCENE)    // 135 worst-case tiles
#define PADMAX  (BATCH + NSCENE * TM)    // 17280 padded rows max

typedef __bf16 bf16x8 __attribute__((ext_vector_type(8)));
typedef float  f32x4  __attribute__((ext_vector_type(4)));

__device__ __forceinline__ ushort f2bf(float f) {
  union { float f; uint32_t u; } v; v.f = f;
  uint32_t r = (v.u + 0x7FFFu + ((v.u >> 16) & 1u)) >> 16;  // RNE
  return (ushort)r;
}
__device__ __forceinline__ uint32_t pack2(float a, float b) {
  return (uint32_t)f2bf(a) | ((uint32_t)f2bf(b) << 16);
}

// ---- prep: sT[s][n][k] = bf16(W[s][k][n] * gW[0][k][n]) --------------------
template<int K, int N>
__global__ void scale_transpose_k(const float* __restrict__ W,
                                  const float* __restrict__ gW,
                                  ushort* __restrict__ sT) {
  __shared__ float tl[32][33];
  int s = blockIdx.z;
  int n0 = blockIdx.x * 32, k0 = blockIdx.y * 32;
  int tx = threadIdx.x, ty = threadIdx.y;
  const float* Wp = W + (size_t)s * K * N;
#pragma unroll
  for (int i = 0; i < 4; i++) {
    int k = k0 + ty + i * 8;
    tl[ty + i * 8][tx] = Wp[(size_t)k * N + n0 + tx] * gW[(size_t)k * N + n0 + tx];
  }
  __syncthreads();
#pragma unroll
  for (int i = 0; i < 4; i++) {
    int n = n0 + ty + i * 8;
    sT[((size_t)s * N + n) * K + k0 + tx] = f2bf(tl[tx][ty + i * 8]);
  }
}

// ---- prep: fused bias  bias_l[s][o] = b_l[s][o] + gb_l[0][o] ---------------
__global__ void bias_k(const float* __restrict__ b0, const float* __restrict__ gb0,
                       const float* __restrict__ b1, const float* __restrict__ gb1,
                       const float* __restrict__ b2, const float* __restrict__ gb2,
                       float* __restrict__ bias0, float* __restrict__ bias1,
                       float* __restrict__ bias2) {
  int t = blockIdx.x * 256 + threadIdx.x;
  if (t < 7 * 512) bias0[t] = b0[t] + gb0[t & 511];
  else if (t < 7 * 512 + 7 * 256) { int i = t - 7 * 512; bias1[i] = b1[i] + gb1[i & 255]; }
  else if (t < 7 * 512 + 7 * 256 + 7 * 64) { int i = t - 7 * 512 - 7 * 256; bias2[i] = b2[i] + gb2[i & 63]; }
}

// meta layout (ints): [0..7]=counts [8..15]=fill [16..23]=padoff [24]=ntiles
//                     [32..191]=tile_scene [192..351]=tile_row
__global__ void zero_meta_k(int* meta) { if (threadIdx.x < 32) meta[threadIdx.x] = 0; }

__global__ void count_k(const int* __restrict__ scene, int* __restrict__ meta) {
  int i = blockIdx.x * 256 + threadIdx.x;
  if (i < BATCH) atomicAdd(&meta[scene[i] - 1], 1);
}

__global__ void plan_k(int* __restrict__ meta, int* __restrict__ idxp) {
  for (int i = threadIdx.x; i < PADMAX; i += 256) idxp[i] = -1;
  if (threadIdx.x == 0) {
    int po = 0, t = 0;
    for (int s = 0; s < NSCENE; s++) {
      meta[16 + s] = po;
      int c = meta[s];
      int tiles = (c + TM - 1) / TM;
      for (int j = 0; j < tiles; j++) { meta[32 + t] = s; meta[192 + t] = po + j * TM; t++; }
      po += tiles * TM;
    }
    meta[24] = t;
  }
}

__global__ void scatter_k(const int* __restrict__ scene, int* __restrict__ meta,
                          int* __restrict__ idxp) {
  int i = blockIdx.x * 256 + threadIdx.x;
  if (i < BATCH) {
    int s = scene[i] - 1;
    int pos = atomicAdd(&meta[8 + s], 1);
    idxp[meta[16 + s] + pos] = i;
  }
}

// ---- GEMM: C[tile rows x NDIM] = A @ sT^T, per-tile scene weights ----------
// LDS 16B-chunk XOR swizzle: data for (row, kchunk kc) lives at chunk
// row*8 + (kc ^ (row&7))  -> frag ds_read_b128 are conflict-free (2-way).
template<int KDIM, int NDIM, int TN, bool GATHER_A, bool RELU, bool SCATTER_OUT>
__global__ __launch_bounds__(256) void gemm_k(
    const float* __restrict__ xin, const ushort* __restrict__ ain,
    const ushort* __restrict__ bw, const float* __restrict__ bias,
    const int* __restrict__ meta, const int* __restrict__ idxp,
    ushort* __restrict__ hout, float* __restrict__ out) {
  int t = blockIdx.x;
  if (t >= meta[24]) return;
  int sc = meta[32 + t];
  int mrow0 = meta[192 + t];
  int nb = blockIdx.y;

  constexpr int WN = TN / 2;       // wave n-extent (wave tile 64 x WN)
  constexpr int ACCN = WN / 16;

  __shared__ __align__(16) ushort Abuf[TM * 64];
  __shared__ __align__(16) ushort Bbuf[TN * 64];

  int tid = threadIdx.x;
  int lane = tid & 63, wid = tid >> 6;
  int wm = wid >> 1, wn = wid & 1;

  f32x4 acc[4][ACCN];
#pragma unroll
  for (int mt = 0; mt < 4; mt++)
#pragma unroll
    for (int nt = 0; nt < ACCN; nt++) acc[mt][nt] = (f32x4){0.f, 0.f, 0.f, 0.f};

  int idxc[4];
  if (GATHER_A) {
#pragma unroll
    for (int i = 0; i < 4; i++) idxc[i] = idxp[mrow0 + (tid >> 3) + i * 32];
  }

  const ushort* bwS = bw + ((size_t)sc * NDIM + (size_t)nb * TN) * KDIM;

  for (int kb = 0; kb < KDIM / 64; kb++) {
    // ---- stage A tile (TM x 64) ----
    if (GATHER_A) {
#pragma unroll
      for (int i = 0; i < 4; i++) {
        int c = tid + i * 256;
        int row = c >> 3, q = c & 7;
        int kcg = q ^ (row & 7);
        uint4 val;
        int g = idxc[i];
        if (g >= 0) {
          const float4* p = (const float4*)(xin + (size_t)g * 512 + kb * 64 + kcg * 8);
          float4 f0 = p[0], f1 = p[1];
          val.x = pack2(f0.x, f0.y); val.y = pack2(f0.z, f0.w);
          val.z = pack2(f1.x, f1.y); val.w = pack2(f1.z, f1.w);
        } else {
          val = make_uint4(0, 0, 0, 0);
        }
        *(uint4*)(&Abuf[c * 8]) = val;
      }
    } else {
#pragma unroll
      for (int i = 0; i < 4; i++) {
        int c = tid + i * 256;
        int row = c >> 3, q = c & 7;
        int kcg = q ^ (row & 7);
        *(uint4*)(&Abuf[c * 8]) =
            *(const uint4*)(ain + (size_t)(mrow0 + row) * KDIM + kb * 64 + kcg * 8);
      }
    }
    // ---- stage B tile (TN x 64) ----
#pragma unroll
    for (int i = 0; i < TN * 8 / 256; i++) {
      int c = tid + i * 256;
      int row = c >> 3, q = c & 7;
      int kcg = q ^ (row & 7);
      *(uint4*)(&Bbuf[c * 8]) =
          *(const uint4*)(bwS + (size_t)row * KDIM + kb * 64 + kcg * 8);
    }
    __syncthreads();
    // ---- MFMA over the staged 64-K slab ----
#pragma unroll
    for (int kk = 0; kk < 64; kk += 32) {
      bf16x8 af[4], bfr[ACCN];
      int kc = (kk >> 3) + (lane >> 4);
#pragma unroll
      for (int mt = 0; mt < 4; mt++) {
        int row = wm * 64 + mt * 16 + (lane & 15);
        af[mt] = *(const bf16x8*)(&Abuf[(row * 8 + (kc ^ (row & 7))) * 8]);
      }
#pragma unroll
      for (int nt = 0; nt < ACCN; nt++) {
        int row = wn * WN + nt * 16 + (lane & 15);
        bfr[nt] = *(const bf16x8*)(&Bbuf[(row * 8 + (kc ^ (row & 7))) * 8]);
      }
#pragma unroll
      for (int mt = 0; mt < 4; mt++)
#pragma unroll
        for (int nt = 0; nt < ACCN; nt++)
          acc[mt][nt] = __builtin_amdgcn_mfma_f32_16x16x32_bf16(af[mt], bfr[nt], acc[mt][nt], 0, 0, 0);
    }
    __syncthreads();
  }

  // ---- epilogue: bias (+relu) then store ----
  // C/D layout: col = lane&15, row = (lane>>4)*4 + reg   [m89-verified]
  int gidx[4][4];
  if (SCATTER_OUT) {
#pragma unroll
    for (int mt = 0; mt < 4; mt++)
#pragma unroll
      for (int r = 0; r < 4; r++)
        gidx[mt][r] = idxp[mrow0 + wm * 64 + mt * 16 + (lane >> 4) * 4 + r];
  }
#pragma unroll
  for (int mt = 0; mt < 4; mt++) {
    int rl0 = wm * 64 + mt * 16 + (lane >> 4) * 4;
#pragma unroll
    for (int nt = 0; nt < ACCN; nt++) {
      int col = nb * TN + wn * WN + nt * 16 + (lane & 15);
      float bv = bias[sc * NDIM + col];
#pragma unroll
      for (int r = 0; r < 4; r++) {
        float v = acc[mt][nt][r] + bv;
        if (RELU) v = fmaxf(v, 0.f);
        if (SCATTER_OUT) {
          int g = gidx[mt][r];
          if (g >= 0) out[(size_t)g * NDIM + col] = v;
        } else {
          hout[(size_t)(mrow0 + rl0 + r) * NDIM + col] = f2bf(v);
        }
      }
    }
  }
}

extern "C" void kernel_launch(void* const* d_in, const int* in_sizes, int n_in,
                              void* d_out, int out_size, void* d_ws, size_t ws_size,
                              hipStream_t stream) {
  const float* x   = (const float*)d_in[0];
  const int* scene = (const int*)d_in[1];
  const float* W0  = (const float*)d_in[2];
  const float* b0  = (const float*)d_in[3];
  const float* gW0 = (const float*)d_in[4];
  const float* gb0 = (const float*)d_in[5];
  const float* W1  = (const float*)d_in[6];
  const float* b1  = (const float*)d_in[7];
  const float* gW1 = (const float*)d_in[8];
  const float* gb1 = (const float*)d_in[9];
  const float* W2  = (const float*)d_in[10];
  const float* b2  = (const float*)d_in[11];
  const float* gW2 = (const float*)d_in[12];
  const float* gb2 = (const float*)d_in[13];
  float* out = (float*)d_out;

  char* ws = (char*)d_ws;
  size_t off = 0;
  auto alloc = [&](size_t bytes) -> void* {
    void* p = ws + off;
    off = (off + bytes + 255) & ~(size_t)255;
    return p;
  };
  ushort* sT0   = (ushort*)alloc((size_t)7 * 512 * 512 * 2);
  ushort* sT1   = (ushort*)alloc((size_t)7 * 256 * 512 * 2);
  ushort* sT2   = (ushort*)alloc((size_t)7 * 64 * 256 * 2);
  float*  bias0 = (float*)alloc(7 * 512 * 4);
  float*  bias1 = (float*)alloc(7 * 256 * 4);
  float*  bias2 = (float*)alloc(7 * 64 * 4);
  int*    meta  = (int*)alloc(1024 * 4);
  int*    idxp  = (int*)alloc(PADMAX * 4);
  ushort* hc1   = (ushort*)alloc((size_t)PADMAX * 512 * 2);
  ushort* hc2   = (ushort*)alloc((size_t)PADMAX * 256 * 2);
  (void)ws_size; (void)n_in; (void)in_sizes; (void)out_size;

  scale_transpose_k<512, 512><<<dim3(16, 16, 7), dim3(32, 8), 0, stream>>>(W0, gW0, sT0);
  scale_transpose_k<512, 256><<<dim3(8, 16, 7), dim3(32, 8), 0, stream>>>(W1, gW1, sT1);
  scale_transpose_k<256, 64><<<dim3(2, 8, 7), dim3(32, 8), 0, stream>>>(W2, gW2, sT2);
  bias_k<<<dim3(23), 256, 0, stream>>>(b0, gb0, b1, gb1, b2, gb2, bias0, bias1, bias2);
  zero_meta_k<<<1, 64, 0, stream>>>(meta);
  count_k<<<64, 256, 0, stream>>>(scene, meta);
  plan_k<<<1, 256, 0, stream>>>(meta, idxp);
  scatter_k<<<64, 256, 0, stream>>>(scene, meta, idxp);

  gemm_k<512, 512, 128, true,  true,  false><<<dim3(MT_MAX, 4), 256, 0, stream>>>(
      x, nullptr, sT0, bias0, meta, idxp, hc1, nullptr);
  gemm_k<512, 256, 128, false, true,  false><<<dim3(MT_MAX, 2), 256, 0, stream>>>(
      nullptr, hc1, sT1, bias1, meta, idxp, hc2, nullptr);
  gemm_k<256, 64, 64,  false, false, true ><<<dim3(MT_MAX, 1), 256, 0, stream>>>(
      nullptr, hc2, sT2, bias2, meta, idxp, nullptr, out);
}

// Round 2
// 177.051 us; speedup vs baseline: 1.8112x; 1.8112x over previous
//
#include <hip/hip_runtime.h>
#include <stdint.h>

// STAR-DNN: per-sample scene-selected 3-layer MLP.
// R1: replaced global-atomic count/scatter (87 us each -- 7-address atomic
// serialization) with per-block LDS histograms + deterministic block bases.

#define BATCH   16384
#define NSCENE  7
#define TM      128
#define NBLK    (BATCH / 256)            // 64 count/scatter blocks
#define MT_MAX  (BATCH / TM + NSCENE)    // 135 worst-case tiles
#define PADMAX  (BATCH + NSCENE * TM)    // 17280 padded rows max

typedef __bf16 bf16x8 __attribute__((ext_vector_type(8)));
typedef float  f32x4  __attribute__((ext_vector_type(4)));

__device__ __forceinline__ ushort f2bf(float f) {
  union { float f; uint32_t u; } v; v.f = f;
  uint32_t r = (v.u + 0x7FFFu + ((v.u >> 16) & 1u)) >> 16;  // RNE
  return (ushort)r;
}
__device__ __forceinline__ uint32_t pack2(float a, float b) {
  return (uint32_t)f2bf(a) | ((uint32_t)f2bf(b) << 16);
}

// ---- prep: sT[s][n][k] = bf16(W[s][k][n] * gW[0][k][n]) --------------------
template<int K, int N>
__global__ void scale_transpose_k(const float* __restrict__ W,
                                  const float* __restrict__ gW,
                                  ushort* __restrict__ sT) {
  __shared__ float tl[32][33];
  int s = blockIdx.z;
  int n0 = blockIdx.x * 32, k0 = blockIdx.y * 32;
  int tx = threadIdx.x, ty = threadIdx.y;
  const float* Wp = W + (size_t)s * K * N;
#pragma unroll
  for (int i = 0; i < 4; i++) {
    int k = k0 + ty + i * 8;
    tl[ty + i * 8][tx] = Wp[(size_t)k * N + n0 + tx] * gW[(size_t)k * N + n0 + tx];
  }
  __syncthreads();
#pragma unroll
  for (int i = 0; i < 4; i++) {
    int n = n0 + ty + i * 8;
    sT[((size_t)s * N + n) * K + k0 + tx] = f2bf(tl[tx][ty + i * 8]);
  }
}

// ---- prep: fused bias  bias_l[s][o] = b_l[s][o] + gb_l[0][o] ---------------
__global__ void bias_k(const float* __restrict__ b0, const float* __restrict__ gb0,
                       const float* __restrict__ b1, const float* __restrict__ gb1,
                       const float* __restrict__ b2, const float* __restrict__ gb2,
                       float* __restrict__ bias0, float* __restrict__ bias1,
                       float* __restrict__ bias2) {
  int t = blockIdx.x * 256 + threadIdx.x;
  if (t < 7 * 512) bias0[t] = b0[t] + gb0[t & 511];
  else if (t < 7 * 512 + 7 * 256) { int i = t - 7 * 512; bias1[i] = b1[i] + gb1[i & 255]; }
  else if (t < 7 * 512 + 7 * 256 + 7 * 64) { int i = t - 7 * 512 - 7 * 256; bias2[i] = b2[i] + gb2[i & 63]; }
}

// meta layout (ints): [16..23]=padoff [24]=ntiles [32..191]=tile_scene
//                     [192..351]=tile_row
// bcnt[b*7+s]  = per-block per-scene counts
// bbase[b*7+s] = padoff[s] + exclusive prefix of bcnt over blocks

__global__ void count_k(const int* __restrict__ scene, int* __restrict__ bcnt) {
  __shared__ int l[NSCENE];
  if (threadIdx.x < NSCENE) l[threadIdx.x] = 0;
  __syncthreads();
  int i = blockIdx.x * 256 + threadIdx.x;
  atomicAdd(&l[scene[i] - 1], 1);   // LDS atomic: cheap
  __syncthreads();
  if (threadIdx.x < NSCENE) bcnt[blockIdx.x * NSCENE + threadIdx.x] = l[threadIdx.x];
}

__global__ void plan_k(const int* __restrict__ bcnt, int* __restrict__ meta,
                       int* __restrict__ bbase) {
  __shared__ int tot[NSCENE];
  if (threadIdx.x < NSCENE) {
    int c = 0;
    for (int b = 0; b < NBLK; b++) c += bcnt[b * NSCENE + threadIdx.x];
    tot[threadIdx.x] = c;
  }
  __syncthreads();
  if (threadIdx.x == 0) {
    int po = 0, t = 0;
    for (int s = 0; s < NSCENE; s++) {
      meta[16 + s] = po;
      int tiles = (tot[s] + TM - 1) / TM;
      for (int j = 0; j < tiles; j++) { meta[32 + t] = s; meta[192 + t] = po + j * TM; t++; }
      po += tiles * TM;
    }
    meta[24] = t;
  }
  __syncthreads();
  if (threadIdx.x < NSCENE) {
    int s = threadIdx.x;
    int run = meta[16 + s];
    for (int b = 0; b < NBLK; b++) { bbase[b * NSCENE + s] = run; run += bcnt[b * NSCENE + s]; }
  }
}

__global__ void fill_k(int* __restrict__ idxp) {
  int i = blockIdx.x * 256 + threadIdx.x;
  if (i < PADMAX) idxp[i] = -1;
}

__global__ void scatter_k(const int* __restrict__ scene,
                          const int* __restrict__ bbase, int* __restrict__ idxp) {
  __shared__ int l[NSCENE];
  if (threadIdx.x < NSCENE) l[threadIdx.x] = 0;
  __syncthreads();
  int i = blockIdx.x * 256 + threadIdx.x;
  int s = scene[i] - 1;
  int pos = atomicAdd(&l[s], 1);    // LDS atomic: local rank
  idxp[bbase[blockIdx.x * NSCENE + s] + pos] = i;
}

// ---- GEMM: C[tile rows x NDIM] = A @ sT^T, per-tile scene weights ----------
// LDS 16B-chunk XOR swizzle: data for (row, kchunk kc) lives at chunk
// row*8 + (kc ^ (row&7))  -> frag ds_read_b128 are conflict-free (2-way).
template<int KDIM, int NDIM, int TN, bool GATHER_A, bool RELU, bool SCATTER_OUT>
__global__ __launch_bounds__(256) void gemm_k(
    const float* __restrict__ xin, const ushort* __restrict__ ain,
    const ushort* __restrict__ bw, const float* __restrict__ bias,
    const int* __restrict__ meta, const int* __restrict__ idxp,
    ushort* __restrict__ hout, float* __restrict__ out) {
  int t = blockIdx.x;
  if (t >= meta[24]) return;
  int sc = meta[32 + t];
  int mrow0 = meta[192 + t];
  int nb = blockIdx.y;

  constexpr int WN = TN / 2;       // wave n-extent (wave tile 64 x WN)
  constexpr int ACCN = WN / 16;

  __shared__ __align__(16) ushort Abuf[TM * 64];
  __shared__ __align__(16) ushort Bbuf[TN * 64];

  int tid = threadIdx.x;
  int lane = tid & 63, wid = tid >> 6;
  int wm = wid >> 1, wn = wid & 1;

  f32x4 acc[4][ACCN];
#pragma unroll
  for (int mt = 0; mt < 4; mt++)
#pragma unroll
    for (int nt = 0; nt < ACCN; nt++) acc[mt][nt] = (f32x4){0.f, 0.f, 0.f, 0.f};

  int idxc[4];
  if (GATHER_A) {
#pragma unroll
    for (int i = 0; i < 4; i++) idxc[i] = idxp[mrow0 + (tid >> 3) + i * 32];
  }

  const ushort* bwS = bw + ((size_t)sc * NDIM + (size_t)nb * TN) * KDIM;

  for (int kb = 0; kb < KDIM / 64; kb++) {
    // ---- stage A tile (TM x 64) ----
    if (GATHER_A) {
#pragma unroll
      for (int i = 0; i < 4; i++) {
        int c = tid + i * 256;
        int row = c >> 3, q = c & 7;
        int kcg = q ^ (row & 7);
        uint4 val;
        int g = idxc[i];
        if (g >= 0) {
          const float4* p = (const float4*)(xin + (size_t)g * 512 + kb * 64 + kcg * 8);
          float4 f0 = p[0], f1 = p[1];
          val.x = pack2(f0.x, f0.y); val.y = pack2(f0.z, f0.w);
          val.z = pack2(f1.x, f1.y); val.w = pack2(f1.z, f1.w);
        } else {
          val = make_uint4(0, 0, 0, 0);
        }
        *(uint4*)(&Abuf[c * 8]) = val;
      }
    } else {
#pragma unroll
      for (int i = 0; i < 4; i++) {
        int c = tid + i * 256;
        int row = c >> 3, q = c & 7;
        int kcg = q ^ (row & 7);
        *(uint4*)(&Abuf[c * 8]) =
            *(const uint4*)(ain + (size_t)(mrow0 + row) * KDIM + kb * 64 + kcg * 8);
      }
    }
    // ---- stage B tile (TN x 64) ----
#pragma unroll
    for (int i = 0; i < TN * 8 / 256; i++) {
      int c = tid + i * 256;
      int row = c >> 3, q = c & 7;
      int kcg = q ^ (row & 7);
      *(uint4*)(&Bbuf[c * 8]) =
          *(const uint4*)(bwS + (size_t)row * KDIM + kb * 64 + kcg * 8);
    }
    __syncthreads();
    // ---- MFMA over the staged 64-K slab ----
#pragma unroll
    for (int kk = 0; kk < 64; kk += 32) {
      bf16x8 af[4], bfr[ACCN];
      int kc = (kk >> 3) + (lane >> 4);
#pragma unroll
      for (int mt = 0; mt < 4; mt++) {
        int row = wm * 64 + mt * 16 + (lane & 15);
        af[mt] = *(const bf16x8*)(&Abuf[(row * 8 + (kc ^ (row & 7))) * 8]);
      }
#pragma unroll
      for (int nt = 0; nt < ACCN; nt++) {
        int row = wn * WN + nt * 16 + (lane & 15);
        bfr[nt] = *(const bf16x8*)(&Bbuf[(row * 8 + (kc ^ (row & 7))) * 8]);
      }
#pragma unroll
      for (int mt = 0; mt < 4; mt++)
#pragma unroll
        for (int nt = 0; nt < ACCN; nt++)
          acc[mt][nt] = __builtin_amdgcn_mfma_f32_16x16x32_bf16(af[mt], bfr[nt], acc[mt][nt], 0, 0, 0);
    }
    __syncthreads();
  }

  // ---- epilogue: bias (+relu) then store ----
  // C/D layout: col = lane&15, row = (lane>>4)*4 + reg   [m89-verified]
  int gidx[4][4];
  if (SCATTER_OUT) {
#pragma unroll
    for (int mt = 0; mt < 4; mt++)
#pragma unroll
      for (int r = 0; r < 4; r++)
        gidx[mt][r] = idxp[mrow0 + wm * 64 + mt * 16 + (lane >> 4) * 4 + r];
  }
#pragma unroll
  for (int mt = 0; mt < 4; mt++) {
    int rl0 = wm * 64 + mt * 16 + (lane >> 4) * 4;
#pragma unroll
    for (int nt = 0; nt < ACCN; nt++) {
      int col = nb * TN + wn * WN + nt * 16 + (lane & 15);
      float bv = bias[sc * NDIM + col];
#pragma unroll
      for (int r = 0; r < 4; r++) {
        float v = acc[mt][nt][r] + bv;
        if (RELU) v = fmaxf(v, 0.f);
        if (SCATTER_OUT) {
          int g = gidx[mt][r];
          if (g >= 0) out[(size_t)g * NDIM + col] = v;
        } else {
          hout[(size_t)(mrow0 + rl0 + r) * NDIM + col] = f2bf(v);
        }
      }
    }
  }
}

extern "C" void kernel_launch(void* const* d_in, const int* in_sizes, int n_in,
                              void* d_out, int out_size, void* d_ws, size_t ws_size,
                              hipStream_t stream) {
  const float* x   = (const float*)d_in[0];
  const int* scene = (const int*)d_in[1];
  const float* W0  = (const float*)d_in[2];
  const float* b0  = (const float*)d_in[3];
  const float* gW0 = (const float*)d_in[4];
  const float* gb0 = (const float*)d_in[5];
  const float* W1  = (const float*)d_in[6];
  const float* b1  = (const float*)d_in[7];
  const float* gW1 = (const float*)d_in[8];
  const float* gb1 = (const float*)d_in[9];
  const float* W2  = (const float*)d_in[10];
  const float* b2  = (const float*)d_in[11];
  const float* gW2 = (const float*)d_in[12];
  const float* gb2 = (const float*)d_in[13];
  float* out = (float*)d_out;

  char* ws = (char*)d_ws;
  size_t off = 0;
  auto alloc = [&](size_t bytes) -> void* {
    void* p = ws + off;
    off = (off + bytes + 255) & ~(size_t)255;
    return p;
  };
  ushort* sT0   = (ushort*)alloc((size_t)7 * 512 * 512 * 2);
  ushort* sT1   = (ushort*)alloc((size_t)7 * 256 * 512 * 2);
  ushort* sT2   = (ushort*)alloc((size_t)7 * 64 * 256 * 2);
  float*  bias0 = (float*)alloc(7 * 512 * 4);
  float*  bias1 = (float*)alloc(7 * 256 * 4);
  float*  bias2 = (float*)alloc(7 * 64 * 4);
  int*    meta  = (int*)alloc(1024 * 4);
  int*    bcnt  = (int*)alloc(NBLK * NSCENE * 4);
  int*    bbase = (int*)alloc(NBLK * NSCENE * 4);
  int*    idxp  = (int*)alloc(PADMAX * 4);
  ushort* hc1   = (ushort*)alloc((size_t)PADMAX * 512 * 2);
  ushort* hc2   = (ushort*)alloc((size_t)PADMAX * 256 * 2);
  (void)ws_size; (void)n_in; (void)in_sizes; (void)out_size;

  scale_transpose_k<512, 512><<<dim3(16, 16, 7), dim3(32, 8), 0, stream>>>(W0, gW0, sT0);
  scale_transpose_k<512, 256><<<dim3(8, 16, 7), dim3(32, 8), 0, stream>>>(W1, gW1, sT1);
  scale_transpose_k<256, 64><<<dim3(2, 8, 7), dim3(32, 8), 0, stream>>>(W2, gW2, sT2);
  bias_k<<<dim3(23), 256, 0, stream>>>(b0, gb0, b1, gb1, b2, gb2, bias0, bias1, bias2);
  count_k<<<NBLK, 256, 0, stream>>>(scene, bcnt);
  plan_k<<<1, 256, 0, stream>>>(bcnt, meta, bbase);
  fill_k<<<(PADMAX + 255) / 256, 256, 0, stream>>>(idxp);
  scatter_k<<<NBLK, 256, 0, stream>>>(scene, bbase, idxp);

  gemm_k<512, 512, 128, true,  true,  false><<<dim3(MT_MAX, 4), 256, 0, stream>>>(
      x, nullptr, sT0, bias0, meta, idxp, hc1, nullptr);
  gemm_k<512, 256, 128, false, true,  false><<<dim3(MT_MAX, 2), 256, 0, stream>>>(
      nullptr, hc1, sT1, bias1, meta, idxp, hc2, nullptr);
  gemm_k<256, 64, 64,  false, false, true ><<<dim3(MT_MAX, 1), 256, 0, stream>>>(
      nullptr, hc2, sT2, bias2, meta, idxp, nullptr, out);
}

// Round 3
// 166.695 us; speedup vs baseline: 1.9238x; 1.0621x over previous
//
#include <hip/hip_runtime.h>
#include <hip/hip_bf16.h>
#include <stdint.h>

// STAR-DNN: per-sample scene-selected 3-layer MLP.
// R1: LDS-histogram count/scatter (no global atomics).
// R2: global_load_lds (16B DMA) staging for all non-gather tiles, packed
//     v_cvt_pk_bf16_f32 for the L0 gather, fused prep (11 -> 6 launches).

#define BATCH   16384
#define NSCENE  7
#define TM      128
#define NBLK    (BATCH / 256)            // 64 count/scatter blocks
#define MT_MAX  (BATCH / TM + NSCENE)    // 135 worst-case tiles
#define PADMAX  (BATCH + NSCENE * TM)    // 17280 padded rows max

typedef __bf16 bf16x8 __attribute__((ext_vector_type(8)));
typedef float  f32x4  __attribute__((ext_vector_type(4)));

__device__ __forceinline__ ushort f2bf(float f) {
  union { float f; uint32_t u; } v; v.f = f;
  uint32_t r = (v.u + 0x7FFFu + ((v.u >> 16) & 1u)) >> 16;  // RNE
  return (ushort)r;
}
__device__ __forceinline__ uint32_t pk2(float a, float b) {
  union { __hip_bfloat162 h; uint32_t u; } cv;
  cv.h = __float22bfloat162_rn(float2{a, b});   // v_cvt_pk_bf16_f32 on gfx950
  return cv.u;
}
// async 16B global->LDS DMA; lds base must be wave-uniform (lane*16 implicit)
__device__ __forceinline__ void async16(const void* g, void* lds) {
  __builtin_amdgcn_global_load_lds(
      (const __attribute__((address_space(1))) uint32_t*)g,
      (__attribute__((address_space(3))) uint32_t*)lds, 16, 0, 0);
}

// ---- fused prep: W scale+transpose (x3 layers), bias fuse, scene count ----
// sT[s][n][k] = bf16(W[s][k][n] * gW[0][k][n]);  32x32 tiles, 256 thr.
__device__ __forceinline__ void st_tile(const float* __restrict__ W,
                                        const float* __restrict__ gW,
                                        ushort* __restrict__ sT,
                                        int K, int N, int s, int n0, int k0,
                                        int tid) {
  __shared__ float tl[32][33];
  int tx = tid & 31, ty = tid >> 5;
  const float* Wp = W + (size_t)s * K * N;
#pragma unroll
  for (int i = 0; i < 4; i++) {
    int k = k0 + ty + i * 8;
    tl[ty + i * 8][tx] = Wp[(size_t)k * N + n0 + tx] * gW[(size_t)k * N + n0 + tx];
  }
  __syncthreads();
#pragma unroll
  for (int i = 0; i < 4; i++) {
    int n = n0 + ty + i * 8;
    sT[((size_t)s * N + n) * K + k0 + tx] = f2bf(tl[tx][ty + i * 8]);
  }
}

#define NB_W0 (16 * 16 * 7)
#define NB_W1 (8 * 16 * 7)
#define NB_W2 (2 * 8 * 7)
#define NB_BIAS 23
#define NB_CNT NBLK

__global__ __launch_bounds__(256) void prep_k(
    const float* __restrict__ W0, const float* __restrict__ gW0,
    const float* __restrict__ W1, const float* __restrict__ gW1,
    const float* __restrict__ W2, const float* __restrict__ gW2,
    const float* __restrict__ b0, const float* __restrict__ gb0,
    const float* __restrict__ b1, const float* __restrict__ gb1,
    const float* __restrict__ b2, const float* __restrict__ gb2,
    const int* __restrict__ scene,
    ushort* __restrict__ sT0, ushort* __restrict__ sT1, ushort* __restrict__ sT2,
    float* __restrict__ bias0, float* __restrict__ bias1, float* __restrict__ bias2,
    int* __restrict__ bcnt) {
  int bid = blockIdx.x, tid = threadIdx.x;
  if (bid < NB_W0) {
    int l = bid;
    st_tile(W0, gW0, sT0, 512, 512, l / 256, (l % 16) * 32, ((l / 16) % 16) * 32, tid);
  } else if (bid < NB_W0 + NB_W1) {
    int l = bid - NB_W0;
    st_tile(W1, gW1, sT1, 512, 256, l / 128, (l % 8) * 32, ((l / 8) % 16) * 32, tid);
  } else if (bid < NB_W0 + NB_W1 + NB_W2) {
    int l = bid - NB_W0 - NB_W1;
    st_tile(W2, gW2, sT2, 256, 64, l / 16, (l % 2) * 32, ((l / 2) % 8) * 32, tid);
  } else if (bid < NB_W0 + NB_W1 + NB_W2 + NB_BIAS) {
    int t = (bid - NB_W0 - NB_W1 - NB_W2) * 256 + tid;
    if (t < 7 * 512) bias0[t] = b0[t] + gb0[t & 511];
    else if (t < 7 * 512 + 7 * 256) { int i = t - 7 * 512; bias1[i] = b1[i] + gb1[i & 255]; }
    else if (t < 7 * 512 + 7 * 256 + 7 * 64) { int i = t - 7 * 512 - 7 * 256; bias2[i] = b2[i] + gb2[i & 63]; }
  } else {
    __shared__ int l[NSCENE];
    if (tid < NSCENE) l[tid] = 0;
    __syncthreads();
    int blk = bid - NB_W0 - NB_W1 - NB_W2 - NB_BIAS;
    atomicAdd(&l[scene[blk * 256 + tid] - 1], 1);   // LDS atomic
    __syncthreads();
    if (tid < NSCENE) bcnt[blk * NSCENE + tid] = l[tid];
  }
}

// meta: [16..23]=padoff [24]=ntiles [32..191]=tile_scene [192..351]=tile_row
__global__ void plan_k(const int* __restrict__ bcnt, int* __restrict__ meta,
                       int* __restrict__ bbase, int* __restrict__ idxp) {
  __shared__ int tot[NSCENE], pstart[NSCENE], pend[NSCENE];
  int tid = threadIdx.x;
  if (tid < NSCENE) {
    int c = 0;
    for (int b = 0; b < NBLK; b++) c += bcnt[b * NSCENE + tid];
    tot[tid] = c;
  }
  __syncthreads();
  if (tid == 0) {
    int po = 0, t = 0;
    for (int s = 0; s < NSCENE; s++) {
      meta[16 + s] = po;
      int tiles = (tot[s] + TM - 1) / TM;
      pstart[s] = po + tot[s];
      pend[s] = po + tiles * TM;
      for (int j = 0; j < tiles; j++) { meta[32 + t] = s; meta[192 + t] = po + j * TM; t++; }
      po += tiles * TM;
    }
    meta[24] = t;
  }
  __syncthreads();
  if (tid < NSCENE) {
    int run = meta[16 + tid];
    for (int b = 0; b < NBLK; b++) { bbase[b * NSCENE + tid] = run; run += bcnt[b * NSCENE + tid]; }
  }
  for (int s = 0; s < NSCENE; s++)
    for (int i = pstart[s] + tid; i < pend[s]; i += 256) idxp[i] = -1;
}

__global__ void scatter_k(const int* __restrict__ scene,
                          const int* __restrict__ bbase, int* __restrict__ idxp) {
  __shared__ int l[NSCENE];
  if (threadIdx.x < NSCENE) l[threadIdx.x] = 0;
  __syncthreads();
  int i = blockIdx.x * 256 + threadIdx.x;
  int s = scene[i] - 1;
  int pos = atomicAdd(&l[s], 1);    // LDS atomic: local rank
  idxp[bbase[blockIdx.x * NSCENE + s] + pos] = i;
}

// ---- GEMM: C[tile rows x NDIM] = A @ sT^T, per-tile scene weights ----------
// LDS 16B-chunk XOR swizzle: LDS chunk c=row*8+q holds global kchunk
// q^(row&7). Staging is linear-in-lane (chunk=tid+i*256) -> global_load_lds
// compatible; frag ds_read_b128 are 2-way (free) across the wave.
template<int KDIM, int NDIM, int TN, bool GATHER_A, bool RELU, bool SCATTER_OUT>
__global__ __launch_bounds__(256) void gemm_k(
    const float* __restrict__ xin, const ushort* __restrict__ ain,
    const ushort* __restrict__ bw, const float* __restrict__ bias,
    const int* __restrict__ meta, const int* __restrict__ idxp,
    ushort* __restrict__ hout, float* __restrict__ out) {
  int t = blockIdx.x;
  if (t >= meta[24]) return;
  int sc = meta[32 + t];
  int mrow0 = meta[192 + t];
  int nb = blockIdx.y;

  constexpr int WN = TN / 2;       // wave n-extent (wave tile 64 x WN)
  constexpr int ACCN = WN / 16;

  __shared__ __align__(16) ushort Abuf[TM * 64];
  __shared__ __align__(16) ushort Bbuf[TN * 64];

  int tid = threadIdx.x;
  int lane = tid & 63, wid = tid >> 6;
  int wm = wid >> 1, wn = wid & 1;

  f32x4 acc[4][ACCN];
#pragma unroll
  for (int mt = 0; mt < 4; mt++)
#pragma unroll
    for (int nt = 0; nt < ACCN; nt++) acc[mt][nt] = (f32x4){0.f, 0.f, 0.f, 0.f};

  int idxc[4];
  if (GATHER_A) {
#pragma unroll
    for (int i = 0; i < 4; i++) idxc[i] = idxp[mrow0 + (tid >> 3) + i * 32];
  }

  const ushort* bwS = bw + ((size_t)sc * NDIM + (size_t)nb * TN) * KDIM;

  for (int kb = 0; kb < KDIM / 64; kb++) {
    // ---- stage A tile (TM x 64) ----
    if (GATHER_A) {
#pragma unroll
      for (int i = 0; i < 4; i++) {
        int c = tid + i * 256;
        int row = c >> 3, q = c & 7;
        int kg = q ^ (row & 7);
        uint4 val;
        int g = idxc[i];
        if (g >= 0) {
          const float4* p = (const float4*)(xin + (size_t)g * 512 + kb * 64 + kg * 8);
          float4 f0 = p[0], f1 = p[1];
          val.x = pk2(f0.x, f0.y); val.y = pk2(f0.z, f0.w);
          val.z = pk2(f1.x, f1.y); val.w = pk2(f1.z, f1.w);
        } else {
          val = make_uint4(0, 0, 0, 0);
        }
        *(uint4*)(&Abuf[c * 8]) = val;
      }
    } else {
#pragma unroll
      for (int i = 0; i < 4; i++) {
        int c = tid + i * 256;
        int row = c >> 3, q = c & 7;
        int kg = q ^ (row & 7);
        async16(ain + (size_t)(mrow0 + row) * KDIM + kb * 64 + kg * 8,
                &Abuf[(size_t)(i * 256 + wid * 64) * 8]);
      }
    }
    // ---- stage B tile (TN x 64) via DMA ----
#pragma unroll
    for (int i = 0; i < TN * 8 / 256; i++) {
      int c = tid + i * 256;
      int row = c >> 3, q = c & 7;
      int kg = q ^ (row & 7);
      async16(bwS + (size_t)row * KDIM + kb * 64 + kg * 8,
              &Bbuf[(size_t)(i * 256 + wid * 64) * 8]);
    }
    __syncthreads();
    // ---- MFMA over the staged 64-K slab ----
#pragma unroll
    for (int kk = 0; kk < 64; kk += 32) {
      bf16x8 af[4], bfr[ACCN];
      int kc = (kk >> 3) + (lane >> 4);
#pragma unroll
      for (int mt = 0; mt < 4; mt++) {
        int row = wm * 64 + mt * 16 + (lane & 15);
        af[mt] = *(const bf16x8*)(&Abuf[(row * 8 + (kc ^ (row & 7))) * 8]);
      }
#pragma unroll
      for (int nt = 0; nt < ACCN; nt++) {
        int row = wn * WN + nt * 16 + (lane & 15);
        bfr[nt] = *(const bf16x8*)(&Bbuf[(row * 8 + (kc ^ (row & 7))) * 8]);
      }
#pragma unroll
      for (int mt = 0; mt < 4; mt++)
#pragma unroll
        for (int nt = 0; nt < ACCN; nt++)
          acc[mt][nt] = __builtin_amdgcn_mfma_f32_16x16x32_bf16(af[mt], bfr[nt], acc[mt][nt], 0, 0, 0);
    }
    __syncthreads();
  }

  // ---- epilogue: bias (+relu) then store ----
  // C/D layout: col = lane&15, row = (lane>>4)*4 + reg   [m89-verified]
  int gidx[4][4];
  if (SCATTER_OUT) {
#pragma unroll
    for (int mt = 0; mt < 4; mt++)
#pragma unroll
      for (int r = 0; r < 4; r++)
        gidx[mt][r] = idxp[mrow0 + wm * 64 + mt * 16 + (lane >> 4) * 4 + r];
  }
#pragma unroll
  for (int mt = 0; mt < 4; mt++) {
    int rl0 = wm * 64 + mt * 16 + (lane >> 4) * 4;
#pragma unroll
    for (int nt = 0; nt < ACCN; nt++) {
      int col = nb * TN + wn * WN + nt * 16 + (lane & 15);
      float bv = bias[sc * NDIM + col];
#pragma unroll
      for (int r = 0; r < 4; r++) {
        float v = acc[mt][nt][r] + bv;
        if (RELU) v = fmaxf(v, 0.f);
        if (SCATTER_OUT) {
          int g = gidx[mt][r];
          if (g >= 0) out[(size_t)g * NDIM + col] = v;
        } else {
          hout[(size_t)(mrow0 + rl0 + r) * NDIM + col] = f2bf(v);
        }
      }
    }
  }
}

extern "C" void kernel_launch(void* const* d_in, const int* in_sizes, int n_in,
                              void* d_out, int out_size, void* d_ws, size_t ws_size,
                              hipStream_t stream) {
  const float* x   = (const float*)d_in[0];
  const int* scene = (const int*)d_in[1];
  const float* W0  = (const float*)d_in[2];
  const float* b0  = (const float*)d_in[3];
  const float* gW0 = (const float*)d_in[4];
  const float* gb0 = (const float*)d_in[5];
  const float* W1  = (const float*)d_in[6];
  const float* b1  = (const float*)d_in[7];
  const float* gW1 = (const float*)d_in[8];
  const float* gb1 = (const float*)d_in[9];
  const float* W2  = (const float*)d_in[10];
  const float* b2  = (const float*)d_in[11];
  const float* gW2 = (const float*)d_in[12];
  const float* gb2 = (const float*)d_in[13];
  float* out = (float*)d_out;

  char* ws = (char*)d_ws;
  size_t off = 0;
  auto alloc = [&](size_t bytes) -> void* {
    void* p = ws + off;
    off = (off + bytes + 255) & ~(size_t)255;
    return p;
  };
  ushort* sT0   = (ushort*)alloc((size_t)7 * 512 * 512 * 2);
  ushort* sT1   = (ushort*)alloc((size_t)7 * 256 * 512 * 2);
  ushort* sT2   = (ushort*)alloc((size_t)7 * 64 * 256 * 2);
  float*  bias0 = (float*)alloc(7 * 512 * 4);
  float*  bias1 = (float*)alloc(7 * 256 * 4);
  float*  bias2 = (float*)alloc(7 * 64 * 4);
  int*    meta  = (int*)alloc(1024 * 4);
  int*    bcnt  = (int*)alloc(NBLK * NSCENE * 4);
  int*    bbase = (int*)alloc(NBLK * NSCENE * 4);
  int*    idxp  = (int*)alloc(PADMAX * 4);
  ushort* hc1   = (ushort*)alloc((size_t)PADMAX * 512 * 2);
  ushort* hc2   = (ushort*)alloc((size_t)PADMAX * 256 * 2);
  (void)ws_size; (void)n_in; (void)in_sizes; (void)out_size;

  prep_k<<<NB_W0 + NB_W1 + NB_W2 + NB_BIAS + NB_CNT, 256, 0, stream>>>(
      W0, gW0, W1, gW1, W2, gW2, b0, gb0, b1, gb1, b2, gb2, scene,
      sT0, sT1, sT2, bias0, bias1, bias2, bcnt);
  plan_k<<<1, 256, 0, stream>>>(bcnt, meta, bbase, idxp);
  scatter_k<<<NBLK, 256, 0, stream>>>(scene, bbase, idxp);

  gemm_k<512, 512, 128, true,  true,  false><<<dim3(MT_MAX, 4), 256, 0, stream>>>(
      x, nullptr, sT0, bias0, meta, idxp, hc1, nullptr);
  gemm_k<512, 256, 128, false, true,  false><<<dim3(MT_MAX, 2), 256, 0, stream>>>(
      nullptr, hc1, sT1, bias1, meta, idxp, hc2, nullptr);
  gemm_k<256, 64, 64,  false, false, true ><<<dim3(MT_MAX, 1), 256, 0, stream>>>(
      nullptr, hc2, sT2, bias2, meta, idxp, nullptr, out);
}